// Round 1
// baseline (701.936 us; speedup 1.0000x reference)
//
#include <hip/hip_runtime.h>
#include <hip/hip_bf16.h>
#include <cstdint>

typedef float f32x4 __attribute__((ext_vector_type(4)));
typedef __bf16 bf16x8 __attribute__((ext_vector_type(8)));

#define BS 128
#define NSP 196
#define NTM 32
#define DDIM 768

// ---------------- row inverse-norms: inv = 1/(||x||+1e-12) ----------------
__global__ void rownorm_kernel(const float* __restrict__ X, float* __restrict__ inv, int nrows)
{
    int row  = blockIdx.x * 4 + (threadIdx.x >> 6);
    int lane = threadIdx.x & 63;
    if (row >= nrows) return;
    const float4* p = reinterpret_cast<const float4*>(X + (size_t)row * DDIM);
    float ss = 0.f;
#pragma unroll
    for (int c = 0; c < 3; ++c) {            // 768/4 = 192 = 3*64
        float4 v = p[lane + 64 * c];
        ss = fmaf(v.x, v.x, ss); ss = fmaf(v.y, v.y, ss);
        ss = fmaf(v.z, v.z, ss); ss = fmaf(v.w, v.w, ss);
    }
#pragma unroll
    for (int off = 32; off; off >>= 1) ss += __shfl_xor(ss, off, 64);
    if (lane == 0) inv[row] = 1.0f / (sqrtf(ss) + 1e-12f);
}

__device__ inline ushort4 f4_to_bf4(float4 v)
{
    ushort4 u;
    u.x = __builtin_bit_cast(unsigned short, (__bf16)v.x);
    u.y = __builtin_bit_cast(unsigned short, (__bf16)v.y);
    u.z = __builtin_bit_cast(unsigned short, (__bf16)v.z);
    u.w = __builtin_bit_cast(unsigned short, (__bf16)v.w);
    return u;
}

// ---------------- batched cost GEMM:  A = exp(-2*(1 - cos)) ----------------
// Output tile: MT = WROWS*NWAVES rows x BN cols per block; K=768 in steps of 32.
template<int WROWS, int NWAVES, int BN, int NPTS>
__global__ __launch_bounds__(NWAVES * 64)
void cost_gemm(const float* __restrict__ X, const float* __restrict__ Y,
               const float* __restrict__ invx, const float* __restrict__ invy,
               float* __restrict__ Aout)
{
    constexpr int MT = WROWS * NWAVES;
    constexpr int CT = BN / 16;
    constexpr int RT = WROWS / 16;
    constexpr int KP = 40;                    // padded LDS row stride (bf16 elems)
    constexpr int NTH = NWAVES * 64;
    __shared__ __bf16 As[MT][KP];
    __shared__ __bf16 Bs[BN][KP];

    const int b    = blockIdx.y;
    const int row0 = blockIdx.x * MT;
    const int tid  = threadIdx.x;
    const int w    = tid >> 6, lane = tid & 63;
    const int q    = lane >> 4, l16 = lane & 15;
    const float* Xb = X + (size_t)b * NPTS * DDIM;
    const float* Yb = Y + (size_t)b * NPTS * DDIM;

    f32x4 acc[RT][CT];
#pragma unroll
    for (int i = 0; i < RT; ++i)
#pragma unroll
        for (int j = 0; j < CT; ++j) acc[i][j] = f32x4{0.f, 0.f, 0.f, 0.f};

    for (int k0 = 0; k0 < DDIM; k0 += 32) {
        __syncthreads();
        for (int idx = tid * 4; idx < MT * 32; idx += NTH * 4) {
            int r = idx >> 5, kk = idx & 31;
            int gr = row0 + r;
            float4 v = {0.f, 0.f, 0.f, 0.f};
            if (gr < NPTS) v = *reinterpret_cast<const float4*>(Xb + (size_t)gr * DDIM + k0 + kk);
            *reinterpret_cast<ushort4*>(&As[r][kk]) = f4_to_bf4(v);
        }
        for (int idx = tid * 4; idx < BN * 32; idx += NTH * 4) {
            int r = idx >> 5, kk = idx & 31;
            float4 v = {0.f, 0.f, 0.f, 0.f};
            if (r < NPTS) v = *reinterpret_cast<const float4*>(Yb + (size_t)r * DDIM + k0 + kk);
            *reinterpret_cast<ushort4*>(&Bs[r][kk]) = f4_to_bf4(v);
        }
        __syncthreads();

        bf16x8 af[RT];
#pragma unroll
        for (int rt = 0; rt < RT; ++rt)
            af[rt] = *reinterpret_cast<const bf16x8*>(&As[w * WROWS + rt * 16 + l16][q * 8]);
#pragma unroll
        for (int ct = 0; ct < CT; ++ct) {
            bf16x8 bf = *reinterpret_cast<const bf16x8*>(&Bs[ct * 16 + l16][q * 8]);
#pragma unroll
            for (int rt = 0; rt < RT; ++rt)
                acc[rt][ct] = __builtin_amdgcn_mfma_f32_16x16x32_bf16(af[rt], bf, acc[rt][ct], 0, 0, 0);
        }
    }

    // epilogue: C/D layout col = lane&15, row = (lane>>4)*4 + reg
#pragma unroll
    for (int rt = 0; rt < RT; ++rt)
#pragma unroll
        for (int ct = 0; ct < CT; ++ct)
#pragma unroll
            for (int rr = 0; rr < 4; ++rr) {
                int i = row0 + w * WROWS + rt * 16 + q * 4 + rr;
                int j = ct * 16 + l16;
                if (i < NPTS && j < NPTS) {
                    float g  = acc[rt][ct][rr];
                    float cs = g * invx[b * NPTS + i] * invy[b * NPTS + j];
                    float c  = 1.0f - cs;
                    Aout[(size_t)b * NPTS * NPTS + (size_t)i * NPTS + j] = expf(-2.0f * c);
                }
            }
}

// ---------------- IPOT: one block per batch, T lives in LDS ----------------
// Lazy scaling: true T = d_i * T_lds_ij * s_j.  sv_j = s_j * sigma_j.
template<int N>
__device__ void ipot_block(const float* __restrict__ Ag, float* __restrict__ out, float* smem)
{
    constexpr int NG  = 512 / N;
    constexpr float MIU = 1.0f / N;
    float* T      = smem;            // N*N
    float* d      = T + N * N;       // N
    float* s      = d + N;           // N
    float* sv     = s + N;           // N
    float* rowsum = sv + N;          // N
    float* cpart  = rowsum + N;      // NG*N
    float* wsum   = cpart + NG * N;  // 8

    const int tid = threadIdx.x;
    const int w = tid >> 6, lane = tid & 63;

    for (int i = tid; i < N * N; i += 512) T[i] = 1.0f;
    if (tid < N) { d[tid] = 1.0f; s[tid] = 1.0f; sv[tid] = 1.0f / N; }  // sigma0 = 1/m
    __syncthreads();

    for (int it = 0; it < 20; ++it) {
        // pass 1: T <- A * (d∘T∘s);  rowsum_i = sum_j T_ij*sigma_j
        for (int r = w; r < N; r += 8) {
            float dv  = d[r];
            float acc = 0.f;
            for (int j = lane; j < N; j += 64) {
                float a  = Ag[r * N + j];
                float m2 = a * T[r * N + j] * dv;
                T[r * N + j] = m2 * s[j];
                acc = fmaf(m2, sv[j], acc);
            }
#pragma unroll
            for (int off = 32; off; off >>= 1) acc += __shfl_xor(acc, off, 64);
            if (lane == 0) rowsum[r] = acc;
        }
        __syncthreads();
        if (tid < N) d[tid] = MIU / (rowsum[tid] + 1e-6f);   // delta (pending row scale)
        __syncthreads();
        // pass 2: colsum_j = sum_i T_ij * delta_i
        if (tid < N * NG) {
            int g = tid / N, j = tid - g * N;
            float acc = 0.f;
            for (int i = g; i < N; i += NG) acc = fmaf(T[i * N + j], d[i], acc);
            cpart[g * N + j] = acc;
        }
        __syncthreads();
        if (tid < N) {
            float csum = 0.f;
#pragma unroll
            for (int g = 0; g < NG; ++g) csum += cpart[g * N + tid];
            float sg = MIU / (csum + 1e-6f);                 // sigma (pending col scale)
            s[tid] = sg; sv[tid] = sg * sg;                  // sigma_carried == s
        }
        __syncthreads();
    }

    // loss_b = -sum d_i*T_ij*s_j * C_ij,  C = -0.5*log(A)
    float acc = 0.f;
    for (int r = w; r < N; r += 8) {
        float dv = d[r];
        for (int j = lane; j < N; j += 64) {
            float a = Ag[r * N + j];
            float c = -0.5f * logf(a);
            acc = fmaf(dv * T[r * N + j] * s[j], c, acc);
        }
    }
#pragma unroll
    for (int off = 32; off; off >>= 1) acc += __shfl_xor(acc, off, 64);
    if (lane == 0) wsum[w] = acc;
    __syncthreads();
    if (tid == 0) {
        float t = 0.f;
#pragma unroll
        for (int i = 0; i < 8; ++i) t += wsum[i];
        atomicAdd(out, -t * (1.0f / BS));
    }
}

__global__ __launch_bounds__(512)
void ipot_kernel(const float* __restrict__ Asp, const float* __restrict__ Atm,
                 float* __restrict__ out)
{
    __shared__ float smem[39600];   // 158,400 B < 160 KiB
    int b = blockIdx.x;
    if (blockIdx.y == 0)
        ipot_block<NSP>(Asp + (size_t)b * NSP * NSP, out, smem);
    else
        ipot_block<NTM>(Atm + (size_t)b * NTM * NTM, out, smem);
}

extern "C" void kernel_launch(void* const* d_in, const int* in_sizes, int n_in,
                              void* d_out, int out_size, void* d_ws, size_t ws_size,
                              hipStream_t stream)
{
    const float* sp1 = (const float*)d_in[0];
    const float* sp2 = (const float*)d_in[1];
    const float* tm1 = (const float*)d_in[2];
    const float* tm2 = (const float*)d_in[3];
    float* out = (float*)d_out;
    float* ws  = (float*)d_ws;

    float* inx_sp = ws;                         // 128*196
    float* iny_sp = inx_sp + BS * NSP;
    float* inx_tm = iny_sp + BS * NSP;          // 128*32
    float* iny_tm = inx_tm + BS * NTM;
    float* A_sp   = iny_tm + BS * NTM;          // 128*196*196
    float* A_tm   = A_sp + (size_t)BS * NSP * NSP;  // 128*32*32

    rownorm_kernel<<<dim3((BS * NSP) / 4), 256, 0, stream>>>(sp1, inx_sp, BS * NSP);
    rownorm_kernel<<<dim3((BS * NSP) / 4), 256, 0, stream>>>(sp2, iny_sp, BS * NSP);
    rownorm_kernel<<<dim3((BS * NTM) / 4), 256, 0, stream>>>(tm1, inx_tm, BS * NTM);
    rownorm_kernel<<<dim3((BS * NTM) / 4), 256, 0, stream>>>(tm2, iny_tm, BS * NTM);

    cost_gemm<32, 4, 208, NSP><<<dim3(2, BS), 256, 0, stream>>>(sp1, sp2, inx_sp, iny_sp, A_sp);
    cost_gemm<16, 2, 32, NTM><<<dim3(1, BS), 128, 0, stream>>>(tm1, tm2, inx_tm, iny_tm, A_tm);

    hipMemsetAsync(d_out, 0, sizeof(float), stream);

    ipot_kernel<<<dim3(BS, 2), 512, 0, stream>>>(A_sp, A_tm, out);
}

// Round 3
// 320.865 us; speedup vs baseline: 2.1876x; 2.1876x over previous
//
#include <hip/hip_runtime.h>
#include <hip/hip_bf16.h>
#include <cstdint>

typedef float f32x4 __attribute__((ext_vector_type(4)));
typedef __bf16 bf16x8 __attribute__((ext_vector_type(8)));

#define BS 128
#define NSP 196
#define NTM 32
#define DDIM 768

// ---------------- row inverse-norms: inv = 1/(||x||+1e-12) ----------------
__global__ void rownorm_kernel(const float* __restrict__ X, float* __restrict__ inv, int nrows)
{
    int row  = blockIdx.x * 4 + (threadIdx.x >> 6);
    int lane = threadIdx.x & 63;
    if (row >= nrows) return;
    const float4* p = reinterpret_cast<const float4*>(X + (size_t)row * DDIM);
    float ss = 0.f;
#pragma unroll
    for (int c = 0; c < 3; ++c) {            // 768/4 = 192 = 3*64
        float4 v = p[lane + 64 * c];
        ss = fmaf(v.x, v.x, ss); ss = fmaf(v.y, v.y, ss);
        ss = fmaf(v.z, v.z, ss); ss = fmaf(v.w, v.w, ss);
    }
#pragma unroll
    for (int off = 32; off; off >>= 1) ss += __shfl_xor(ss, off, 64);
    if (lane == 0) inv[row] = 1.0f / (sqrtf(ss) + 1e-12f);
}

__device__ inline ushort4 f4_to_bf4(float4 v)
{
    ushort4 u;
    u.x = __builtin_bit_cast(unsigned short, (__bf16)v.x);
    u.y = __builtin_bit_cast(unsigned short, (__bf16)v.y);
    u.z = __builtin_bit_cast(unsigned short, (__bf16)v.z);
    u.w = __builtin_bit_cast(unsigned short, (__bf16)v.w);
    return u;
}

// ---------------- batched cost GEMM:  A = exp(-2*(1 - cos)) ----------------
template<int WROWS, int NWAVES, int BN, int NPTS>
__global__ __launch_bounds__(NWAVES * 64)
void cost_gemm(const float* __restrict__ X, const float* __restrict__ Y,
               const float* __restrict__ invx, const float* __restrict__ invy,
               float* __restrict__ Aout)
{
    constexpr int MT = WROWS * NWAVES;
    constexpr int CT = BN / 16;
    constexpr int RT = WROWS / 16;
    constexpr int KP = 40;                    // padded LDS row stride (bf16 elems)
    constexpr int NTH = NWAVES * 64;
    __shared__ __bf16 As[MT][KP];
    __shared__ __bf16 Bs[BN][KP];

    const int b    = blockIdx.y;
    const int row0 = blockIdx.x * MT;
    const int tid  = threadIdx.x;
    const int w    = tid >> 6, lane = tid & 63;
    const int q    = lane >> 4, l16 = lane & 15;
    const float* Xb = X + (size_t)b * NPTS * DDIM;
    const float* Yb = Y + (size_t)b * NPTS * DDIM;

    f32x4 acc[RT][CT];
#pragma unroll
    for (int i = 0; i < RT; ++i)
#pragma unroll
        for (int j = 0; j < CT; ++j) acc[i][j] = f32x4{0.f, 0.f, 0.f, 0.f};

    for (int k0 = 0; k0 < DDIM; k0 += 32) {
        __syncthreads();
        for (int idx = tid * 4; idx < MT * 32; idx += NTH * 4) {
            int r = idx >> 5, kk = idx & 31;
            int gr = row0 + r;
            float4 v = {0.f, 0.f, 0.f, 0.f};
            if (gr < NPTS) v = *reinterpret_cast<const float4*>(Xb + (size_t)gr * DDIM + k0 + kk);
            *reinterpret_cast<ushort4*>(&As[r][kk]) = f4_to_bf4(v);
        }
        for (int idx = tid * 4; idx < BN * 32; idx += NTH * 4) {
            int r = idx >> 5, kk = idx & 31;
            float4 v = {0.f, 0.f, 0.f, 0.f};
            if (r < NPTS) v = *reinterpret_cast<const float4*>(Yb + (size_t)r * DDIM + k0 + kk);
            *reinterpret_cast<ushort4*>(&Bs[r][kk]) = f4_to_bf4(v);
        }
        __syncthreads();

        bf16x8 af[RT];
#pragma unroll
        for (int rt = 0; rt < RT; ++rt)
            af[rt] = *reinterpret_cast<const bf16x8*>(&As[w * WROWS + rt * 16 + l16][q * 8]);
#pragma unroll
        for (int ct = 0; ct < CT; ++ct) {
            bf16x8 bf = *reinterpret_cast<const bf16x8*>(&Bs[ct * 16 + l16][q * 8]);
#pragma unroll
            for (int rt = 0; rt < RT; ++rt)
                acc[rt][ct] = __builtin_amdgcn_mfma_f32_16x16x32_bf16(af[rt], bf, acc[rt][ct], 0, 0, 0);
        }
    }

    // epilogue: C/D layout col = lane&15, row = (lane>>4)*4 + reg
#pragma unroll
    for (int rt = 0; rt < RT; ++rt)
#pragma unroll
        for (int ct = 0; ct < CT; ++ct)
#pragma unroll
            for (int rr = 0; rr < 4; ++rr) {
                int i = row0 + w * WROWS + rt * 16 + q * 4 + rr;
                int j = ct * 16 + l16;
                if (i < NPTS && j < NPTS) {
                    float g  = acc[rt][ct][rr];
                    float cs = g * invx[b * NPTS + i] * invy[b * NPTS + j];
                    float c  = 1.0f - cs;
                    Aout[(size_t)b * NPTS * NPTS + (size_t)i * NPTS + j] = expf(-2.0f * c);
                }
            }
}

// ---------------- spatial IPOT: T (=P) in registers, A bf16 in LDS ----------
// Lane (w, rq=lane>>4, cl=lane&15) owns rows {rq+4w+32k, k<7}, cols {8cl+128m+e}.
// Stable recursion: delta and sigma are folded into P every iteration, so P is
// exactly the reference T (bounded ~1/(n*m)); sr[] carries sigma for next iter.
#define SP_CPAD 256
#define SP_RPAD 224
#define SP_K 7
#define SP_CPS 260

__global__ __launch_bounds__(512, 1)
void ipot_sp_kernel(const float* __restrict__ Ag, float* __restrict__ out)
{
    __shared__ __bf16 Ash[SP_RPAD * SP_CPAD];     // 114688 B
    __shared__ float  cpart[32 * SP_CPS];         // 33280 B
    __shared__ float  svec[SP_CPAD];
    __shared__ float  wsum[8];

    const int b = blockIdx.x;
    const float* Ab = Ag + (size_t)b * NSP * NSP;
    const int tid = threadIdx.x;
    const int w = tid >> 6, lane = tid & 63;
    const int rq = lane >> 4, cl = lane & 15;
    constexpr float MIU = 1.f / NSP;

    {   // zero A (covers col/row padding)
        f32x4 z = {0.f, 0.f, 0.f, 0.f};
        f32x4* az = reinterpret_cast<f32x4*>(Ash);
#pragma unroll
        for (int i = 0; i < SP_RPAD * SP_CPAD * 2 / 16 / 512; ++i) az[tid + 512 * i] = z;
    }
    __syncthreads();
    for (int idx = tid; idx < (NSP * NSP / 4); idx += 512) {
        int r = idx / 49;
        int c4 = (idx - r * 49) * 4;
        float4 v = *reinterpret_cast<const float4*>(Ab + r * NSP + c4);
        *reinterpret_cast<ushort4*>(&Ash[r * SP_CPAD + c4]) = f4_to_bf4(v);
    }
    __syncthreads();

    int ri[SP_K];
    float P[SP_K][16];
#pragma unroll
    for (int k = 0; k < SP_K; ++k) {
        ri[k] = rq + 4 * w + 32 * k;
#pragma unroll
        for (int e = 0; e < 16; ++e) P[k][e] = 1.f;
    }
    const int colbase = 8 * cl;

    float sr[16];                   // sigma (carry) for my 16 cols; sigma0 = 1/m
#pragma unroll
    for (int e = 0; e < 16; ++e) {
        int j = colbase + (e < 8 ? e : 120 + e);   // e<8: colbase+e ; else colbase+128+(e-8)
        sr[e] = (j < NSP) ? MIU : 0.f;
    }

    for (int it = 0; it < 20; ++it) {
        // T = A*T ; rowsum_i = sum_j T_ij*sigma_j ; delta = miu/(rowsum+eps); T *= delta
#pragma unroll
        for (int k = 0; k < SP_K; ++k) {
            bf16x8 a0 = *reinterpret_cast<const bf16x8*>(&Ash[ri[k] * SP_CPAD + colbase]);
            bf16x8 a1 = *reinterpret_cast<const bf16x8*>(&Ash[ri[k] * SP_CPAD + colbase + 128]);
            float acc = 0.f;
#pragma unroll
            for (int e = 0; e < 8; ++e) {
                P[k][e] *= (float)a0[e];
                acc = fmaf(P[k][e], sr[e], acc);
            }
#pragma unroll
            for (int e = 0; e < 8; ++e) {
                P[k][8 + e] *= (float)a1[e];
                acc = fmaf(P[k][8 + e], sr[8 + e], acc);
            }
            acc += __shfl_xor(acc, 1);
            acc += __shfl_xor(acc, 2);
            acc += __shfl_xor(acc, 4);
            acc += __shfl_xor(acc, 8);
            float delta = MIU / (acc + 1e-6f);
#pragma unroll
            for (int e = 0; e < 16; ++e) P[k][e] *= delta;
        }
        // colsum_j = sum_i T_ij (delta already folded)
        float cs[16];
#pragma unroll
        for (int e = 0; e < 16; ++e) {
            float c = 0.f;
#pragma unroll
            for (int k = 0; k < SP_K; ++k) c += P[k][e];
            cs[e] = c;
        }
        {
            int g = w * 4 + rq;
#pragma unroll
            for (int m = 0; m < 2; ++m)
#pragma unroll
                for (int h = 0; h < 2; ++h) {
                    float4 o;
                    o.x = cs[m * 8 + h * 4 + 0]; o.y = cs[m * 8 + h * 4 + 1];
                    o.z = cs[m * 8 + h * 4 + 2]; o.w = cs[m * 8 + h * 4 + 3];
                    *reinterpret_cast<float4*>(&cpart[g * SP_CPS + colbase + 128 * m + 4 * h]) = o;
                }
        }
        __syncthreads();
        if (tid < SP_CPAD) {
            float c0 = 0.f, c1 = 0.f, c2 = 0.f, c3 = 0.f;
#pragma unroll
            for (int g = 0; g < 32; g += 4) {
                c0 += cpart[(g + 0) * SP_CPS + tid];
                c1 += cpart[(g + 1) * SP_CPS + tid];
                c2 += cpart[(g + 2) * SP_CPS + tid];
                c3 += cpart[(g + 3) * SP_CPS + tid];
            }
            float csum = (c0 + c1) + (c2 + c3);
            svec[tid] = (tid < NSP) ? (MIU / (csum + 1e-6f)) : 0.f;
        }
        __syncthreads();
        // fold sigma into T; sr becomes sigma-carry for next iteration
#pragma unroll
        for (int m = 0; m < 2; ++m)
#pragma unroll
            for (int h = 0; h < 2; ++h)
                *reinterpret_cast<float4*>(&sr[m * 8 + h * 4]) =
                    *reinterpret_cast<const float4*>(&svec[colbase + 128 * m + 4 * h]);
#pragma unroll
        for (int k = 0; k < SP_K; ++k)
#pragma unroll
            for (int e = 0; e < 16; ++e) P[k][e] *= sr[e];
        __syncthreads();
    }

    // loss_b = -sum T_ij * C_ij,  C = -0.5*log(A)
    float acc = 0.f;
#pragma unroll
    for (int k = 0; k < SP_K; ++k) {
        bf16x8 a0 = *reinterpret_cast<const bf16x8*>(&Ash[ri[k] * SP_CPAD + colbase]);
        bf16x8 a1 = *reinterpret_cast<const bf16x8*>(&Ash[ri[k] * SP_CPAD + colbase + 128]);
#pragma unroll
        for (int e = 0; e < 8; ++e) {
            float c0 = -0.5f * __logf(fmaxf((float)a0[e], 1e-30f));
            float c1 = -0.5f * __logf(fmaxf((float)a1[e], 1e-30f));
            acc = fmaf(P[k][e], c0, acc);
            acc = fmaf(P[k][8 + e], c1, acc);
        }
    }
#pragma unroll
    for (int off = 32; off; off >>= 1) acc += __shfl_xor(acc, off);
    if (lane == 0) wsum[w] = acc;
    __syncthreads();
    if (tid == 0) {
        float t = 0.f;
#pragma unroll
        for (int i = 0; i < 8; ++i) t += wsum[i];
        atomicAdd(out, -t * (1.f / BS));
    }
}

// ---------------- temporal IPOT: one wave per batch, all-register -----------
// Lane (rh=lane>>5, cj=lane&31) owns rows {rh+2k, k<16}, col cj.
__global__ __launch_bounds__(64, 1)
void ipot_tm_kernel(const float* __restrict__ Ag, float* __restrict__ out)
{
    const int b = blockIdx.x;
    const float* Ab = Ag + (size_t)b * NTM * NTM;
    const int lane = threadIdx.x;
    const int rh = lane >> 5, cj = lane & 31;
    constexpr float MIU = 1.f / NTM;

    float A[16], P[16];
#pragma unroll
    for (int k = 0; k < 16; ++k) {
        A[k] = Ab[(rh + 2 * k) * NTM + cj];
        P[k] = 1.f;
    }
    float sv = MIU;     // sigma carry (my column)

    for (int it = 0; it < 20; ++it) {
#pragma unroll
        for (int k = 0; k < 16; ++k) {
            P[k] *= A[k];
            float acc = P[k] * sv;
            acc += __shfl_xor(acc, 1);
            acc += __shfl_xor(acc, 2);
            acc += __shfl_xor(acc, 4);
            acc += __shfl_xor(acc, 8);
            acc += __shfl_xor(acc, 16);
            float delta = MIU / (acc + 1e-6f);
            P[k] *= delta;
        }
        float cssum = 0.f;
#pragma unroll
        for (int k = 0; k < 16; ++k) cssum += P[k];
        cssum += __shfl_xor(cssum, 32);
        float sg = MIU / (cssum + 1e-6f);
#pragma unroll
        for (int k = 0; k < 16; ++k) P[k] *= sg;
        sv = sg;
    }
    float acc = 0.f;
#pragma unroll
    for (int k = 0; k < 16; ++k) {
        float c = -0.5f * __logf(A[k]);
        acc = fmaf(P[k], c, acc);
    }
#pragma unroll
    for (int off = 32; off; off >>= 1) acc += __shfl_xor(acc, off);
    if (lane == 0) atomicAdd(out, -acc * (1.f / BS));
}

extern "C" void kernel_launch(void* const* d_in, const int* in_sizes, int n_in,
                              void* d_out, int out_size, void* d_ws, size_t ws_size,
                              hipStream_t stream)
{
    const float* sp1 = (const float*)d_in[0];
    const float* sp2 = (const float*)d_in[1];
    const float* tm1 = (const float*)d_in[2];
    const float* tm2 = (const float*)d_in[3];
    float* out = (float*)d_out;
    float* ws  = (float*)d_ws;

    float* inx_sp = ws;                         // 128*196
    float* iny_sp = inx_sp + BS * NSP;
    float* inx_tm = iny_sp + BS * NSP;          // 128*32
    float* iny_tm = inx_tm + BS * NTM;
    float* A_sp   = iny_tm + BS * NTM;          // 128*196*196
    float* A_tm   = A_sp + (size_t)BS * NSP * NSP;  // 128*32*32

    rownorm_kernel<<<dim3((BS * NSP) / 4), 256, 0, stream>>>(sp1, inx_sp, BS * NSP);
    rownorm_kernel<<<dim3((BS * NSP) / 4), 256, 0, stream>>>(sp2, iny_sp, BS * NSP);
    rownorm_kernel<<<dim3((BS * NTM) / 4), 256, 0, stream>>>(tm1, inx_tm, BS * NTM);
    rownorm_kernel<<<dim3((BS * NTM) / 4), 256, 0, stream>>>(tm2, iny_tm, BS * NTM);

    cost_gemm<32, 4, 208, NSP><<<dim3(2, BS), 256, 0, stream>>>(sp1, sp2, inx_sp, iny_sp, A_sp);
    cost_gemm<16, 2, 32, NTM><<<dim3(1, BS), 128, 0, stream>>>(tm1, tm2, inx_tm, iny_tm, A_tm);

    hipMemsetAsync(d_out, 0, sizeof(float), stream);

    ipot_sp_kernel<<<dim3(BS), 512, 0, stream>>>(A_sp, out);
    ipot_tm_kernel<<<dim3(BS), 64, 0, stream>>>(A_tm, out);
}

// Round 5
// 304.196 us; speedup vs baseline: 2.3075x; 1.0548x over previous
//
#include <hip/hip_runtime.h>
#include <hip/hip_bf16.h>
#include <cstdint>

typedef float f32x4 __attribute__((ext_vector_type(4)));
typedef __bf16 bf16x8 __attribute__((ext_vector_type(8)));

#define BS 128
#define NSP 196
#define NTM 32
#define DDIM 768

// ---------------- row inverse-norms: inv = 1/(||x||+1e-12) ----------------
__global__ void rownorm_kernel(const float* __restrict__ X, float* __restrict__ inv, int nrows)
{
    int row  = blockIdx.x * 4 + (threadIdx.x >> 6);
    int lane = threadIdx.x & 63;
    if (row >= nrows) return;
    const float4* p = reinterpret_cast<const float4*>(X + (size_t)row * DDIM);
    float ss = 0.f;
#pragma unroll
    for (int c = 0; c < 3; ++c) {
        float4 v = p[lane + 64 * c];
        ss = fmaf(v.x, v.x, ss); ss = fmaf(v.y, v.y, ss);
        ss = fmaf(v.z, v.z, ss); ss = fmaf(v.w, v.w, ss);
    }
#pragma unroll
    for (int off = 32; off; off >>= 1) ss += __shfl_xor(ss, off, 64);
    if (lane == 0) inv[row] = 1.0f / (sqrtf(ss) + 1e-12f);
}

__device__ inline ushort4 f4_to_bf4(float4 v)
{
    ushort4 u;
    u.x = __builtin_bit_cast(unsigned short, (__bf16)v.x);
    u.y = __builtin_bit_cast(unsigned short, (__bf16)v.y);
    u.z = __builtin_bit_cast(unsigned short, (__bf16)v.z);
    u.w = __builtin_bit_cast(unsigned short, (__bf16)v.w);
    return u;
}

__device__ inline bf16x8 f4x2_to_bf8(float4 lo, float4 hi)
{
    bf16x8 r;
    r[0] = (__bf16)lo.x; r[1] = (__bf16)lo.y; r[2] = (__bf16)lo.z; r[3] = (__bf16)lo.w;
    r[4] = (__bf16)hi.x; r[5] = (__bf16)hi.y; r[6] = (__bf16)hi.z; r[7] = (__bf16)hi.w;
    return r;
}

// ======================= spatial cost GEMM ===========================
// Grid 512 = 8 XCD * 16 batch * 4 coltile (XCD-swizzled). Block 448 thr (7 waves).
// Tile: 224 rows x 64 cols, BK=64, dbuf LDS with XOR slot swizzle, 1 barrier/iter.
// Output: A = exp(2*cos - 2) as bf16 into A_sp[b][256 rows][256 cols] (pre-zeroed).
#define GA_LDS 18432          // (224*64 + 64*64) bf16 per buffer
__global__ __launch_bounds__(448)
void cost_gemm_sp(const float* __restrict__ X, const float* __restrict__ Y,
                  const float* __restrict__ invx, const float* __restrict__ invy,
                  __bf16* __restrict__ Aout)
{
    __shared__ __bf16 lds[2 * GA_LDS];

    const int flat  = blockIdx.x;
    const int xcd   = flat & 7;
    const int s     = flat >> 3;
    const int b     = xcd * 16 + (s >> 2);
    const int ctile = s & 3;
    const int n0    = (ctile < 3) ? ctile * 64 : 132;

    const int tid  = threadIdx.x;
    const int w    = tid >> 6, lane = tid & 63;
    const int q    = lane >> 4, l16 = lane & 15;
    const int srow = tid >> 3;          // 0..55
    const int sslt = tid & 7;           // 0..7

    const float* Yb = Y + (size_t)b * NSP * DDIM;

    float4 aL[4], aH[4], bL, bH, b2L, b2H;

    auto LOADS = [&](int k0) {
#pragma unroll
        for (int p = 0; p < 4; ++p) {
            int gr = b * NSP + srow + 56 * p;            // may run past batch rows
            gr = min(gr, BS * NSP - 1);                  // clamp: no OOB fault
            const float* sp = X + (size_t)gr * DDIM + k0 + sslt * 8;
            aL[p] = *reinterpret_cast<const float4*>(sp);
            aH[p] = *reinterpret_cast<const float4*>(sp + 4);
        }
        {
            const float* sp = Yb + (size_t)(n0 + srow) * DDIM + k0 + sslt * 8;
            bL = *reinterpret_cast<const float4*>(sp);
            bH = *reinterpret_cast<const float4*>(sp + 4);
        }
        if (tid < 64) {
            const float* sp = Yb + (size_t)(n0 + 56 + srow) * DDIM + k0 + sslt * 8;
            b2L = *reinterpret_cast<const float4*>(sp);
            b2H = *reinterpret_cast<const float4*>(sp + 4);
        }
    };
    auto WRITES = [&](int buf) {
#pragma unroll
        for (int p = 0; p < 4; ++p) {
            int r = srow + 56 * p;
            *reinterpret_cast<bf16x8*>(&lds[buf * GA_LDS + r * 64 + ((sslt ^ (r & 7)) << 3)]) =
                f4x2_to_bf8(aL[p], aH[p]);
        }
        {
            int r = srow;
            *reinterpret_cast<bf16x8*>(&lds[buf * GA_LDS + 14336 + r * 64 + ((sslt ^ (r & 7)) << 3)]) =
                f4x2_to_bf8(bL, bH);
        }
        if (tid < 64) {
            int r = 56 + srow;
            *reinterpret_cast<bf16x8*>(&lds[buf * GA_LDS + 14336 + r * 64 + ((sslt ^ (r & 7)) << 3)]) =
                f4x2_to_bf8(b2L, b2H);
        }
    };

    f32x4 acc[2][4];
#pragma unroll
    for (int i = 0; i < 2; ++i)
#pragma unroll
        for (int j = 0; j < 4; ++j) acc[i][j] = f32x4{0.f, 0.f, 0.f, 0.f};

    LOADS(0);
    int buf = 0;
    for (int kt = 0; kt < 12; ++kt) {
        WRITES(buf);
        if (kt < 11) LOADS((kt + 1) * 64);
        __syncthreads();
#pragma unroll
        for (int ks = 0; ks < 2; ++ks) {
            bf16x8 af[2], bf[4];
#pragma unroll
            for (int rt = 0; rt < 2; ++rt) {
                int r = w * 32 + rt * 16 + l16;
                af[rt] = *reinterpret_cast<const bf16x8*>(
                    &lds[buf * GA_LDS + r * 64 + ((((ks * 4 + q)) ^ (r & 7)) << 3)]);
            }
#pragma unroll
            for (int ct = 0; ct < 4; ++ct) {
                int r = ct * 16 + l16;
                bf[ct] = *reinterpret_cast<const bf16x8*>(
                    &lds[buf * GA_LDS + 14336 + r * 64 + ((((ks * 4 + q)) ^ (r & 7)) << 3)]);
            }
#pragma unroll
            for (int ct = 0; ct < 4; ++ct)
#pragma unroll
                for (int rt = 0; rt < 2; ++rt)
                    acc[rt][ct] = __builtin_amdgcn_mfma_f32_16x16x32_bf16(af[rt], bf[ct], acc[rt][ct], 0, 0, 0);
        }
        __syncthreads();
        buf ^= 1;
    }

    // epilogue: i = w*32 + rt*16 + q*4 + rr (X row), j = n0 + ct*16 + l16 (Y row, always <196)
    float ivy[4];
#pragma unroll
    for (int ct = 0; ct < 4; ++ct) ivy[ct] = invy[b * NSP + n0 + ct * 16 + l16];
#pragma unroll
    for (int rt = 0; rt < 2; ++rt)
#pragma unroll
        for (int rr = 0; rr < 4; ++rr) {
            int i = w * 32 + rt * 16 + q * 4 + rr;
            if (i < NSP) {
                float ivx = invx[b * NSP + i];
#pragma unroll
                for (int ct = 0; ct < 4; ++ct) {
                    int j = n0 + ct * 16 + l16;
                    float cs = acc[rt][ct][rr] * ivx * ivy[ct];
                    float a  = __expf(2.0f * cs - 2.0f);
                    Aout[(size_t)b * 65536 + (size_t)i * 256 + j] = (__bf16)a;
                }
            }
        }
}

// ---------------- temporal cost GEMM (old structure, f32 out) ----------------
template<int WROWS, int NWAVES, int BN, int NPTS>
__global__ __launch_bounds__(NWAVES * 64)
void cost_gemm(const float* __restrict__ X, const float* __restrict__ Y,
               const float* __restrict__ invx, const float* __restrict__ invy,
               float* __restrict__ Aout)
{
    constexpr int MT = WROWS * NWAVES;
    constexpr int CT = BN / 16;
    constexpr int RT = WROWS / 16;
    constexpr int KP = 40;
    constexpr int NTH = NWAVES * 64;
    __shared__ __bf16 As[MT][KP];
    __shared__ __bf16 Bs[BN][KP];

    const int b    = blockIdx.y;
    const int row0 = blockIdx.x * MT;
    const int tid  = threadIdx.x;
    const int w    = tid >> 6, lane = tid & 63;
    const int q    = lane >> 4, l16 = lane & 15;
    const float* Xb = X + (size_t)b * NPTS * DDIM;
    const float* Yb = Y + (size_t)b * NPTS * DDIM;

    f32x4 acc[RT][CT];
#pragma unroll
    for (int i = 0; i < RT; ++i)
#pragma unroll
        for (int j = 0; j < CT; ++j) acc[i][j] = f32x4{0.f, 0.f, 0.f, 0.f};

    for (int k0 = 0; k0 < DDIM; k0 += 32) {
        __syncthreads();
        for (int idx = tid * 4; idx < MT * 32; idx += NTH * 4) {
            int r = idx >> 5, kk = idx & 31;
            int gr = row0 + r;
            float4 v = {0.f, 0.f, 0.f, 0.f};
            if (gr < NPTS) v = *reinterpret_cast<const float4*>(Xb + (size_t)gr * DDIM + k0 + kk);
            *reinterpret_cast<ushort4*>(&As[r][kk]) = f4_to_bf4(v);
        }
        for (int idx = tid * 4; idx < BN * 32; idx += NTH * 4) {
            int r = idx >> 5, kk = idx & 31;
            float4 v = {0.f, 0.f, 0.f, 0.f};
            if (r < NPTS) v = *reinterpret_cast<const float4*>(Yb + (size_t)r * DDIM + k0 + kk);
            *reinterpret_cast<ushort4*>(&Bs[r][kk]) = f4_to_bf4(v);
        }
        __syncthreads();

        bf16x8 af[RT];
#pragma unroll
        for (int rt = 0; rt < RT; ++rt)
            af[rt] = *reinterpret_cast<const bf16x8*>(&As[w * WROWS + rt * 16 + l16][q * 8]);
#pragma unroll
        for (int ct = 0; ct < CT; ++ct) {
            bf16x8 bfr = *reinterpret_cast<const bf16x8*>(&Bs[ct * 16 + l16][q * 8]);
#pragma unroll
            for (int rt = 0; rt < RT; ++rt)
                acc[rt][ct] = __builtin_amdgcn_mfma_f32_16x16x32_bf16(af[rt], bfr, acc[rt][ct], 0, 0, 0);
        }
    }

#pragma unroll
    for (int rt = 0; rt < RT; ++rt)
#pragma unroll
        for (int ct = 0; ct < CT; ++ct)
#pragma unroll
            for (int rr = 0; rr < 4; ++rr) {
                int i = row0 + w * WROWS + rt * 16 + q * 4 + rr;
                int j = ct * 16 + l16;
                if (i < NPTS && j < NPTS) {
                    float g  = acc[rt][ct][rr];
                    float cs = g * invx[b * NPTS + i] * invy[b * NPTS + j];
                    Aout[(size_t)b * NPTS * NPTS + (size_t)i * NPTS + j] = expf(-2.0f * (1.0f - cs));
                }
            }
}

// ================= spatial IPOT v3: T in regs, A bf16 from L2 ===============
// 1024 thr (16 waves). Lane (w, rq=lane>>4, cl=lane&15) owns rows rq+4w+64k
// (k<3; wave 0 also row 192+rq), cols {8cl+e, 8cl+128+e : e<8}.
__global__ __launch_bounds__(1024)
void ipot_sp2(const __bf16* __restrict__ Ag, float* __restrict__ out)
{
    __shared__ float cpart[64 * 260];     // 66,560 B
    __shared__ float svec[2][272];
    __shared__ float wsum[16];

    const int b = blockIdx.x;
    const __bf16* Ab = Ag + (size_t)b * 65536;
    const int tid = threadIdx.x;
    const int w = tid >> 6, lane = tid & 63;
    const int rq = lane >> 4, cl = lane & 15;
    const int colbase = cl * 8;
    constexpr float MIU = 1.f / NSP;

    int ri[4];
#pragma unroll
    for (int k = 0; k < 3; ++k) ri[k] = rq + 4 * w + 64 * k;
    ri[3] = 192 + rq;                     // valid only for w==0
    const bool w0 = (w == 0);

    float P[4][16];
#pragma unroll
    for (int k = 0; k < 4; ++k)
#pragma unroll
        for (int e = 0; e < 16; ++e) P[k][e] = 1.f;

    float sr[16];
#pragma unroll
    for (int e = 0; e < 16; ++e) {
        int j = (e < 8) ? (colbase + e) : (colbase + 128 + (e - 8));
        sr[e] = (j < NSP) ? MIU : 0.f;
    }

    for (int it = 0; it < 20; ++it) {
        float cs[16];
#pragma unroll
        for (int e = 0; e < 16; ++e) cs[e] = 0.f;

#pragma unroll
        for (int k = 0; k < 4; ++k) {
            if (k < 3 || w0) {
                const __bf16* ap = Ab + ri[k] * 256 + colbase;
                bf16x8 a0 = *reinterpret_cast<const bf16x8*>(ap);
                bf16x8 a1 = *reinterpret_cast<const bf16x8*>(ap + 128);
                float racc = 0.f;
#pragma unroll
                for (int e = 0; e < 8; ++e) {
                    P[k][e] *= (float)a0[e];
                    racc = fmaf(P[k][e], sr[e], racc);
                }
#pragma unroll
                for (int e = 0; e < 8; ++e) {
                    P[k][8 + e] *= (float)a1[e];
                    racc = fmaf(P[k][8 + e], sr[8 + e], racc);
                }
                racc += __shfl_xor(racc, 1);
                racc += __shfl_xor(racc, 2);
                racc += __shfl_xor(racc, 4);
                racc += __shfl_xor(racc, 8);
                float delta = MIU / (racc + 1e-6f);
#pragma unroll
                for (int e = 0; e < 16; ++e) {
                    P[k][e] *= delta;
                    cs[e] += P[k][e];
                }
            }
        }
        {
            int g = w * 4 + rq;
            float* cp = &cpart[g * 260 + colbase];
            *reinterpret_cast<f32x4*>(cp)     = f32x4{cs[0], cs[1], cs[2], cs[3]};
            *reinterpret_cast<f32x4*>(cp + 4) = f32x4{cs[4], cs[5], cs[6], cs[7]};
            float* cp2 = cp + 128;
            *reinterpret_cast<f32x4*>(cp2)     = f32x4{cs[8], cs[9], cs[10], cs[11]};
            *reinterpret_cast<f32x4*>(cp2 + 4) = f32x4{cs[12], cs[13], cs[14], cs[15]};
        }
        __syncthreads();
        if (tid < 256) {
            float s0 = 0.f, s1 = 0.f, s2 = 0.f, s3 = 0.f;
#pragma unroll
            for (int g = 0; g < 64; g += 4) {
                s0 += cpart[(g + 0) * 260 + tid];
                s1 += cpart[(g + 1) * 260 + tid];
                s2 += cpart[(g + 2) * 260 + tid];
                s3 += cpart[(g + 3) * 260 + tid];
            }
            float sum = (s0 + s1) + (s2 + s3);
            svec[it & 1][tid] = (tid < NSP) ? (MIU / (sum + 1e-6f)) : 0.f;
        }
        __syncthreads();
        {
            const float* sv = svec[it & 1];
            f32x4 t0 = *reinterpret_cast<const f32x4*>(&sv[colbase]);
            f32x4 t1 = *reinterpret_cast<const f32x4*>(&sv[colbase + 4]);
            f32x4 t2 = *reinterpret_cast<const f32x4*>(&sv[colbase + 128]);
            f32x4 t3 = *reinterpret_cast<const f32x4*>(&sv[colbase + 132]);
            sr[0] = t0.x; sr[1] = t0.y; sr[2] = t0.z; sr[3] = t0.w;
            sr[4] = t1.x; sr[5] = t1.y; sr[6] = t1.z; sr[7] = t1.w;
            sr[8] = t2.x; sr[9] = t2.y; sr[10] = t2.z; sr[11] = t2.w;
            sr[12] = t3.x; sr[13] = t3.y; sr[14] = t3.z; sr[15] = t3.w;
        }
#pragma unroll
        for (int k = 0; k < 4; ++k)
#pragma unroll
            for (int e = 0; e < 16; ++e) P[k][e] *= sr[e];
    }

    // loss: -sum T*C, C = -0.5*log(A)
    float acc = 0.f;
#pragma unroll
    for (int k = 0; k < 4; ++k) {
        if (k < 3 || w0) {
            const __bf16* ap = Ab + ri[k] * 256 + colbase;
            bf16x8 a0 = *reinterpret_cast<const bf16x8*>(ap);
            bf16x8 a1 = *reinterpret_cast<const bf16x8*>(ap + 128);
#pragma unroll
            for (int e = 0; e < 8; ++e) {
                float c0 = -0.5f * __logf(fmaxf((float)a0[e], 1e-30f));
                float c1 = -0.5f * __logf(fmaxf((float)a1[e], 1e-30f));
                acc = fmaf(P[k][e], c0, acc);
                acc = fmaf(P[k][8 + e], c1, acc);
            }
        }
    }
#pragma unroll
    for (int off = 32; off; off >>= 1) acc += __shfl_xor(acc, off);
    if (lane == 0) wsum[w] = acc;
    __syncthreads();
    if (tid == 0) {
        float t = 0.f;
#pragma unroll
        for (int i = 0; i < 16; ++i) t += wsum[i];
        atomicAdd(out, -t * (1.f / BS));
    }
}

// ---------------- temporal IPOT: one wave per batch, all-register -----------
__global__ __launch_bounds__(64, 1)
void ipot_tm_kernel(const float* __restrict__ Ag, float* __restrict__ out)
{
    const int b = blockIdx.x;
    const float* Ab = Ag + (size_t)b * NTM * NTM;
    const int lane = threadIdx.x;
    const int rh = lane >> 5, cj = lane & 31;
    constexpr float MIU = 1.f / NTM;

    float A[16], P[16];
#pragma unroll
    for (int k = 0; k < 16; ++k) {
        A[k] = Ab[(rh + 2 * k) * NTM + cj];
        P[k] = 1.f;
    }
    float sv = MIU;

    for (int it = 0; it < 20; ++it) {
#pragma unroll
        for (int k = 0; k < 16; ++k) {
            P[k] *= A[k];
            float acc = P[k] * sv;
            acc += __shfl_xor(acc, 1);
            acc += __shfl_xor(acc, 2);
            acc += __shfl_xor(acc, 4);
            acc += __shfl_xor(acc, 8);
            acc += __shfl_xor(acc, 16);
            float delta = MIU / (acc + 1e-6f);
            P[k] *= delta;
        }
        float cssum = 0.f;
#pragma unroll
        for (int k = 0; k < 16; ++k) cssum += P[k];
        cssum += __shfl_xor(cssum, 32);
        float sg = MIU / (cssum + 1e-6f);
#pragma unroll
        for (int k = 0; k < 16; ++k) P[k] *= sg;
        sv = sg;
    }
    float acc = 0.f;
#pragma unroll
    for (int k = 0; k < 16; ++k) {
        float c = -0.5f * __logf(A[k]);
        acc = fmaf(P[k], c, acc);
    }
#pragma unroll
    for (int off = 32; off; off >>= 1) acc += __shfl_xor(acc, off);
    if (lane == 0) atomicAdd(out, -acc * (1.f / BS));
}

extern "C" void kernel_launch(void* const* d_in, const int* in_sizes, int n_in,
                              void* d_out, int out_size, void* d_ws, size_t ws_size,
                              hipStream_t stream)
{
    const float* sp1 = (const float*)d_in[0];
    const float* sp2 = (const float*)d_in[1];
    const float* tm1 = (const float*)d_in[2];
    const float* tm2 = (const float*)d_in[3];
    float* out = (float*)d_out;
    float* ws  = (float*)d_ws;

    float* inx_sp = ws;                          // 25088
    float* iny_sp = inx_sp + BS * NSP;           // 25088
    float* inx_tm = iny_sp + BS * NSP;           // 4096
    float* iny_tm = inx_tm + BS * NTM;           // 4096
    float* A_tm   = iny_tm + BS * NTM;           // 131072 f32
    __bf16* A_sp  = (__bf16*)(ws + 189440);      // 128*256*256 bf16 = 16.78 MB

    rownorm_kernel<<<dim3((BS * NSP) / 4), 256, 0, stream>>>(sp1, inx_sp, BS * NSP);
    rownorm_kernel<<<dim3((BS * NSP) / 4), 256, 0, stream>>>(sp2, iny_sp, BS * NSP);
    rownorm_kernel<<<dim3((BS * NTM) / 4), 256, 0, stream>>>(tm1, inx_tm, BS * NTM);
    rownorm_kernel<<<dim3((BS * NTM) / 4), 256, 0, stream>>>(tm2, iny_tm, BS * NTM);

    (void)hipMemsetAsync(A_sp, 0, (size_t)BS * 65536 * 2, stream);

    cost_gemm_sp<<<dim3(512), 448, 0, stream>>>(sp1, sp2, inx_sp, iny_sp, A_sp);
    cost_gemm<16, 2, 32, NTM><<<dim3(1, BS), 128, 0, stream>>>(tm1, tm2, inx_tm, iny_tm, A_tm);

    (void)hipMemsetAsync(d_out, 0, sizeof(float), stream);

    ipot_sp2<<<dim3(BS), 1024, 0, stream>>>(A_sp, out);
    ipot_tm_kernel<<<dim3(BS), 64, 0, stream>>>(A_tm, out);
}

// Round 6
// 222.191 us; speedup vs baseline: 3.1592x; 1.3691x over previous
//
#include <hip/hip_runtime.h>
#include <hip/hip_bf16.h>
#include <cstdint>

typedef float f32x4 __attribute__((ext_vector_type(4)));
typedef __bf16 bf16x8 __attribute__((ext_vector_type(8)));

#define BS 128
#define NSP 196
#define NTM 32
#define DDIM 768

// ---------------- row inverse-norms: inv = 1/(||x||+1e-12) ----------------
__global__ void rownorm_kernel(const float* __restrict__ X, float* __restrict__ inv, int nrows)
{
    int row  = blockIdx.x * 4 + (threadIdx.x >> 6);
    int lane = threadIdx.x & 63;
    if (row >= nrows) return;
    const float4* p = reinterpret_cast<const float4*>(X + (size_t)row * DDIM);
    float ss = 0.f;
#pragma unroll
    for (int c = 0; c < 3; ++c) {
        float4 v = p[lane + 64 * c];
        ss = fmaf(v.x, v.x, ss); ss = fmaf(v.y, v.y, ss);
        ss = fmaf(v.z, v.z, ss); ss = fmaf(v.w, v.w, ss);
    }
#pragma unroll
    for (int off = 32; off; off >>= 1) ss += __shfl_xor(ss, off, 64);
    if (lane == 0) inv[row] = 1.0f / (sqrtf(ss) + 1e-12f);
}

__device__ inline ushort4 f4_to_bf4(float4 v)
{
    ushort4 u;
    u.x = __builtin_bit_cast(unsigned short, (__bf16)v.x);
    u.y = __builtin_bit_cast(unsigned short, (__bf16)v.y);
    u.z = __builtin_bit_cast(unsigned short, (__bf16)v.z);
    u.w = __builtin_bit_cast(unsigned short, (__bf16)v.w);
    return u;
}

__device__ inline bf16x8 f4x2_to_bf8(float4 lo, float4 hi)
{
    bf16x8 r;
    r[0] = (__bf16)lo.x; r[1] = (__bf16)lo.y; r[2] = (__bf16)lo.z; r[3] = (__bf16)lo.w;
    r[4] = (__bf16)hi.x; r[5] = (__bf16)hi.y; r[6] = (__bf16)hi.z; r[7] = (__bf16)hi.w;
    return r;
}

// ======================= spatial cost GEMM ===========================
// Grid 512 = 8 XCD * 16 batch * 4 coltile (XCD-swizzled). Block 448 thr (7 waves).
// Tile: 224 rows x 64 cols, BK=64, dbuf LDS with XOR slot swizzle, 1 barrier/iter.
// Output: A = exp(2*cos - 2) as bf16 into A_sp[b][256 rows][256 cols] (pre-zeroed).
#define GA_LDS 18432          // (224*64 + 64*64) bf16 per buffer
__global__ __launch_bounds__(448)
void cost_gemm_sp(const float* __restrict__ X, const float* __restrict__ Y,
                  const float* __restrict__ invx, const float* __restrict__ invy,
                  __bf16* __restrict__ Aout)
{
    __shared__ __bf16 lds[2 * GA_LDS];

    const int flat  = blockIdx.x;
    const int xcd   = flat & 7;
    const int s     = flat >> 3;
    const int b     = xcd * 16 + (s >> 2);
    const int ctile = s & 3;
    const int n0    = (ctile < 3) ? ctile * 64 : 132;

    const int tid  = threadIdx.x;
    const int w    = tid >> 6, lane = tid & 63;
    const int q    = lane >> 4, l16 = lane & 15;
    const int srow = tid >> 3;          // 0..55
    const int sslt = tid & 7;           // 0..7

    const float* Yb = Y + (size_t)b * NSP * DDIM;

    float4 aL[4], aH[4], bL, bH, b2L, b2H;

    auto LOADS = [&](int k0) {
#pragma unroll
        for (int p = 0; p < 4; ++p) {
            int gr = b * NSP + srow + 56 * p;            // may run past batch rows
            gr = min(gr, BS * NSP - 1);                  // clamp: no OOB fault
            const float* sp = X + (size_t)gr * DDIM + k0 + sslt * 8;
            aL[p] = *reinterpret_cast<const float4*>(sp);
            aH[p] = *reinterpret_cast<const float4*>(sp + 4);
        }
        {
            const float* sp = Yb + (size_t)(n0 + srow) * DDIM + k0 + sslt * 8;
            bL = *reinterpret_cast<const float4*>(sp);
            bH = *reinterpret_cast<const float4*>(sp + 4);
        }
        if (tid < 64) {
            const float* sp = Yb + (size_t)(n0 + 56 + srow) * DDIM + k0 + sslt * 8;
            b2L = *reinterpret_cast<const float4*>(sp);
            b2H = *reinterpret_cast<const float4*>(sp + 4);
        }
    };
    auto WRITES = [&](int buf) {
#pragma unroll
        for (int p = 0; p < 4; ++p) {
            int r = srow + 56 * p;
            *reinterpret_cast<bf16x8*>(&lds[buf * GA_LDS + r * 64 + ((sslt ^ (r & 7)) << 3)]) =
                f4x2_to_bf8(aL[p], aH[p]);
        }
        {
            int r = srow;
            *reinterpret_cast<bf16x8*>(&lds[buf * GA_LDS + 14336 + r * 64 + ((sslt ^ (r & 7)) << 3)]) =
                f4x2_to_bf8(bL, bH);
        }
        if (tid < 64) {
            int r = 56 + srow;
            *reinterpret_cast<bf16x8*>(&lds[buf * GA_LDS + 14336 + r * 64 + ((sslt ^ (r & 7)) << 3)]) =
                f4x2_to_bf8(b2L, b2H);
        }
    };

    f32x4 acc[2][4];
#pragma unroll
    for (int i = 0; i < 2; ++i)
#pragma unroll
        for (int j = 0; j < 4; ++j) acc[i][j] = f32x4{0.f, 0.f, 0.f, 0.f};

    LOADS(0);
    int buf = 0;
    for (int kt = 0; kt < 12; ++kt) {
        WRITES(buf);
        if (kt < 11) LOADS((kt + 1) * 64);
        __syncthreads();
#pragma unroll
        for (int ks = 0; ks < 2; ++ks) {
            bf16x8 af[2], bf[4];
#pragma unroll
            for (int rt = 0; rt < 2; ++rt) {
                int r = w * 32 + rt * 16 + l16;
                af[rt] = *reinterpret_cast<const bf16x8*>(
                    &lds[buf * GA_LDS + r * 64 + ((((ks * 4 + q)) ^ (r & 7)) << 3)]);
            }
#pragma unroll
            for (int ct = 0; ct < 4; ++ct) {
                int r = ct * 16 + l16;
                bf[ct] = *reinterpret_cast<const bf16x8*>(
                    &lds[buf * GA_LDS + 14336 + r * 64 + ((((ks * 4 + q)) ^ (r & 7)) << 3)]);
            }
#pragma unroll
            for (int ct = 0; ct < 4; ++ct)
#pragma unroll
                for (int rt = 0; rt < 2; ++rt)
                    acc[rt][ct] = __builtin_amdgcn_mfma_f32_16x16x32_bf16(af[rt], bf[ct], acc[rt][ct], 0, 0, 0);
        }
        __syncthreads();
        buf ^= 1;
    }

    // epilogue: i = w*32 + rt*16 + q*4 + rr (X row), j = n0 + ct*16 + l16 (Y row, always <196)
    float ivy[4];
#pragma unroll
    for (int ct = 0; ct < 4; ++ct) ivy[ct] = invy[b * NSP + n0 + ct * 16 + l16];
#pragma unroll
    for (int rt = 0; rt < 2; ++rt)
#pragma unroll
        for (int rr = 0; rr < 4; ++rr) {
            int i = w * 32 + rt * 16 + q * 4 + rr;
            if (i < NSP) {
                float ivx = invx[b * NSP + i];
#pragma unroll
                for (int ct = 0; ct < 4; ++ct) {
                    int j = n0 + ct * 16 + l16;
                    float cs = acc[rt][ct][rr] * ivx * ivy[ct];
                    float a  = __expf(2.0f * cs - 2.0f);
                    Aout[(size_t)b * 65536 + (size_t)i * 256 + j] = (__bf16)a;
                }
            }
        }
}

// ---------------- temporal cost GEMM (old structure, f32 out) ----------------
template<int WROWS, int NWAVES, int BN, int NPTS>
__global__ __launch_bounds__(NWAVES * 64)
void cost_gemm(const float* __restrict__ X, const float* __restrict__ Y,
               const float* __restrict__ invx, const float* __restrict__ invy,
               float* __restrict__ Aout)
{
    constexpr int MT = WROWS * NWAVES;
    constexpr int CT = BN / 16;
    constexpr int RT = WROWS / 16;
    constexpr int KP = 40;
    constexpr int NTH = NWAVES * 64;
    __shared__ __bf16 As[MT][KP];
    __shared__ __bf16 Bs[BN][KP];

    const int b    = blockIdx.y;
    const int row0 = blockIdx.x * MT;
    const int tid  = threadIdx.x;
    const int w    = tid >> 6, lane = tid & 63;
    const int q    = lane >> 4, l16 = lane & 15;
    const float* Xb = X + (size_t)b * NPTS * DDIM;
    const float* Yb = Y + (size_t)b * NPTS * DDIM;

    f32x4 acc[RT][CT];
#pragma unroll
    for (int i = 0; i < RT; ++i)
#pragma unroll
        for (int j = 0; j < CT; ++j) acc[i][j] = f32x4{0.f, 0.f, 0.f, 0.f};

    for (int k0 = 0; k0 < DDIM; k0 += 32) {
        __syncthreads();
        for (int idx = tid * 4; idx < MT * 32; idx += NTH * 4) {
            int r = idx >> 5, kk = idx & 31;
            int gr = row0 + r;
            float4 v = {0.f, 0.f, 0.f, 0.f};
            if (gr < NPTS) v = *reinterpret_cast<const float4*>(Xb + (size_t)gr * DDIM + k0 + kk);
            *reinterpret_cast<ushort4*>(&As[r][kk]) = f4_to_bf4(v);
        }
        for (int idx = tid * 4; idx < BN * 32; idx += NTH * 4) {
            int r = idx >> 5, kk = idx & 31;
            float4 v = {0.f, 0.f, 0.f, 0.f};
            if (r < NPTS) v = *reinterpret_cast<const float4*>(Yb + (size_t)r * DDIM + k0 + kk);
            *reinterpret_cast<ushort4*>(&Bs[r][kk]) = f4_to_bf4(v);
        }
        __syncthreads();

        bf16x8 af[RT];
#pragma unroll
        for (int rt = 0; rt < RT; ++rt)
            af[rt] = *reinterpret_cast<const bf16x8*>(&As[w * WROWS + rt * 16 + l16][q * 8]);
#pragma unroll
        for (int ct = 0; ct < CT; ++ct) {
            bf16x8 bfr = *reinterpret_cast<const bf16x8*>(&Bs[ct * 16 + l16][q * 8]);
#pragma unroll
            for (int rt = 0; rt < RT; ++rt)
                acc[rt][ct] = __builtin_amdgcn_mfma_f32_16x16x32_bf16(af[rt], bfr, acc[rt][ct], 0, 0, 0);
        }
    }

#pragma unroll
    for (int rt = 0; rt < RT; ++rt)
#pragma unroll
        for (int ct = 0; ct < CT; ++ct)
#pragma unroll
            for (int rr = 0; rr < 4; ++rr) {
                int i = row0 + w * WROWS + rt * 16 + q * 4 + rr;
                int j = ct * 16 + l16;
                if (i < NPTS && j < NPTS) {
                    float g  = acc[rt][ct][rr];
                    float cs = g * invx[b * NPTS + i] * invy[b * NPTS + j];
                    Aout[(size_t)b * NPTS * NPTS + (size_t)i * NPTS + j] = expf(-2.0f * (1.0f - cs));
                }
            }
}

// ================= spatial IPOT v4: 512 thr, 7 rows/lane, no spill ==========
// Lane (w, rq=lane>>4, cl=lane&15): row-group g = w*4+rq (0..31), rows g+32k
// (k<7, covers 0..223; rows>=196 are zero padding), cols {8cl+e, 8cl+128+e}.
// Batch remapped so block's XCD (blockIdx%8) matches gemm's writer XCD (b>>4).
__global__ __launch_bounds__(512, 2)
void ipot_sp3(const __bf16* __restrict__ Ag, float* __restrict__ out)
{
    __shared__ float cpart[32 * 260];     // 33,280 B
    __shared__ float svec[2][272];
    __shared__ float wsum[8];

    const int B = blockIdx.x;
    const int b = (B & 7) * 16 + (B >> 3);     // XCD-home alignment with gemm
    const __bf16* Ab = Ag + (size_t)b * 65536;
    const int tid = threadIdx.x;
    const int w = tid >> 6, lane = tid & 63;
    const int rq = lane >> 4, cl = lane & 15;
    const int g = w * 4 + rq;                  // 0..31
    const int colbase = cl * 8;
    constexpr float MIU = 1.f / NSP;

    float P[7][16];
#pragma unroll
    for (int k = 0; k < 7; ++k)
#pragma unroll
        for (int e = 0; e < 16; ++e) P[k][e] = 1.f;

    float sr[16];
#pragma unroll
    for (int e = 0; e < 16; ++e) {
        int j = (e < 8) ? (colbase + e) : (colbase + 128 + (e - 8));
        sr[e] = (j < NSP) ? MIU : 0.f;
    }

    for (int it = 0; it < 20; ++it) {
        float cs[16];
#pragma unroll
        for (int e = 0; e < 16; ++e) cs[e] = 0.f;

#pragma unroll
        for (int k = 0; k < 7; ++k) {
            const __bf16* ap = Ab + (g + 32 * k) * 256 + colbase;
            bf16x8 a0 = *reinterpret_cast<const bf16x8*>(ap);
            bf16x8 a1 = *reinterpret_cast<const bf16x8*>(ap + 128);
            float racc = 0.f;
#pragma unroll
            for (int e = 0; e < 8; ++e) {
                P[k][e] *= (float)a0[e];
                racc = fmaf(P[k][e], sr[e], racc);
            }
#pragma unroll
            for (int e = 0; e < 8; ++e) {
                P[k][8 + e] *= (float)a1[e];
                racc = fmaf(P[k][8 + e], sr[8 + e], racc);
            }
            racc += __shfl_xor(racc, 1);
            racc += __shfl_xor(racc, 2);
            racc += __shfl_xor(racc, 4);
            racc += __shfl_xor(racc, 8);
            float delta = MIU / (racc + 1e-6f);
#pragma unroll
            for (int e = 0; e < 16; ++e) {
                P[k][e] *= delta;
                cs[e] += P[k][e];
            }
        }
        {
            float* cp = &cpart[g * 260 + colbase];
            *reinterpret_cast<f32x4*>(cp)     = f32x4{cs[0], cs[1], cs[2], cs[3]};
            *reinterpret_cast<f32x4*>(cp + 4) = f32x4{cs[4], cs[5], cs[6], cs[7]};
            float* cp2 = cp + 128;
            *reinterpret_cast<f32x4*>(cp2)     = f32x4{cs[8], cs[9], cs[10], cs[11]};
            *reinterpret_cast<f32x4*>(cp2 + 4) = f32x4{cs[12], cs[13], cs[14], cs[15]};
        }
        __syncthreads();
        if (tid < 256) {
            float s0 = 0.f, s1 = 0.f, s2 = 0.f, s3 = 0.f;
#pragma unroll
            for (int gg = 0; gg < 32; gg += 4) {
                s0 += cpart[(gg + 0) * 260 + tid];
                s1 += cpart[(gg + 1) * 260 + tid];
                s2 += cpart[(gg + 2) * 260 + tid];
                s3 += cpart[(gg + 3) * 260 + tid];
            }
            float sum = (s0 + s1) + (s2 + s3);
            svec[it & 1][tid] = (tid < NSP) ? (MIU / (sum + 1e-6f)) : 0.f;
        }
        __syncthreads();
        {
            const float* sv = svec[it & 1];
            f32x4 t0 = *reinterpret_cast<const f32x4*>(&sv[colbase]);
            f32x4 t1 = *reinterpret_cast<const f32x4*>(&sv[colbase + 4]);
            f32x4 t2 = *reinterpret_cast<const f32x4*>(&sv[colbase + 128]);
            f32x4 t3 = *reinterpret_cast<const f32x4*>(&sv[colbase + 132]);
            sr[0] = t0.x; sr[1] = t0.y; sr[2] = t0.z; sr[3] = t0.w;
            sr[4] = t1.x; sr[5] = t1.y; sr[6] = t1.z; sr[7] = t1.w;
            sr[8] = t2.x; sr[9] = t2.y; sr[10] = t2.z; sr[11] = t2.w;
            sr[12] = t3.x; sr[13] = t3.y; sr[14] = t3.z; sr[15] = t3.w;
        }
#pragma unroll
        for (int k = 0; k < 7; ++k)
#pragma unroll
            for (int e = 0; e < 16; ++e) P[k][e] *= sr[e];
    }

    // loss: -sum T*C, C = -0.5*log(A)
    float acc = 0.f;
#pragma unroll
    for (int k = 0; k < 7; ++k) {
        const __bf16* ap = Ab + (g + 32 * k) * 256 + colbase;
        bf16x8 a0 = *reinterpret_cast<const bf16x8*>(ap);
        bf16x8 a1 = *reinterpret_cast<const bf16x8*>(ap + 128);
#pragma unroll
        for (int e = 0; e < 8; ++e) {
            float c0 = -0.5f * __logf(fmaxf((float)a0[e], 1e-30f));
            float c1 = -0.5f * __logf(fmaxf((float)a1[e], 1e-30f));
            acc = fmaf(P[k][e], c0, acc);
            acc = fmaf(P[k][8 + e], c1, acc);
        }
    }
#pragma unroll
    for (int off = 32; off; off >>= 1) acc += __shfl_xor(acc, off);
    if (lane == 0) wsum[w] = acc;
    __syncthreads();
    if (tid == 0) {
        float t = 0.f;
#pragma unroll
        for (int i = 0; i < 8; ++i) t += wsum[i];
        atomicAdd(out, -t * (1.f / BS));
    }
}

// ---------------- temporal IPOT: one wave per batch, all-register -----------
__global__ __launch_bounds__(64, 1)
void ipot_tm_kernel(const float* __restrict__ Ag, float* __restrict__ out)
{
    const int b = blockIdx.x;
    const float* Ab = Ag + (size_t)b * NTM * NTM;
    const int lane = threadIdx.x;
    const int rh = lane >> 5, cj = lane & 31;
    constexpr float MIU = 1.f / NTM;

    float A[16], P[16];
#pragma unroll
    for (int k = 0; k < 16; ++k) {
        A[k] = Ab[(rh + 2 * k) * NTM + cj];
        P[k] = 1.f;
    }
    float sv = MIU;

    for (int it = 0; it < 20; ++it) {
#pragma unroll
        for (int k = 0; k < 16; ++k) {
            P[k] *= A[k];
            float acc = P[k] * sv;
            acc += __shfl_xor(acc, 1);
            acc += __shfl_xor(acc, 2);
            acc += __shfl_xor(acc, 4);
            acc += __shfl_xor(acc, 8);
            acc += __shfl_xor(acc, 16);
            float delta = MIU / (acc + 1e-6f);
            P[k] *= delta;
        }
        float cssum = 0.f;
#pragma unroll
        for (int k = 0; k < 16; ++k) cssum += P[k];
        cssum += __shfl_xor(cssum, 32);
        float sg = MIU / (cssum + 1e-6f);
#pragma unroll
        for (int k = 0; k < 16; ++k) P[k] *= sg;
        sv = sg;
    }
    float acc = 0.f;
#pragma unroll
    for (int k = 0; k < 16; ++k) {
        float c = -0.5f * __logf(A[k]);
        acc = fmaf(P[k], c, acc);
    }
#pragma unroll
    for (int off = 32; off; off >>= 1) acc += __shfl_xor(acc, off);
    if (lane == 0) atomicAdd(out, -acc * (1.f / BS));
}

extern "C" void kernel_launch(void* const* d_in, const int* in_sizes, int n_in,
                              void* d_out, int out_size, void* d_ws, size_t ws_size,
                              hipStream_t stream)
{
    const float* sp1 = (const float*)d_in[0];
    const float* sp2 = (const float*)d_in[1];
    const float* tm1 = (const float*)d_in[2];
    const float* tm2 = (const float*)d_in[3];
    float* out = (float*)d_out;
    float* ws  = (float*)d_ws;

    float* inx_sp = ws;                          // 25088
    float* iny_sp = inx_sp + BS * NSP;           // 25088
    float* inx_tm = iny_sp + BS * NSP;           // 4096
    float* iny_tm = inx_tm + BS * NTM;           // 4096
    float* A_tm   = iny_tm + BS * NTM;           // 131072 f32
    __bf16* A_sp  = (__bf16*)(ws + 189440);      // 128*256*256 bf16 = 16.78 MB

    rownorm_kernel<<<dim3((BS * NSP) / 4), 256, 0, stream>>>(sp1, inx_sp, BS * NSP);
    rownorm_kernel<<<dim3((BS * NSP) / 4), 256, 0, stream>>>(sp2, iny_sp, BS * NSP);
    rownorm_kernel<<<dim3((BS * NTM) / 4), 256, 0, stream>>>(tm1, inx_tm, BS * NTM);
    rownorm_kernel<<<dim3((BS * NTM) / 4), 256, 0, stream>>>(tm2, iny_tm, BS * NTM);

    (void)hipMemsetAsync(A_sp, 0, (size_t)BS * 65536 * 2, stream);

    cost_gemm_sp<<<dim3(512), 448, 0, stream>>>(sp1, sp2, inx_sp, iny_sp, A_sp);
    cost_gemm<16, 2, 32, NTM><<<dim3(1, BS), 128, 0, stream>>>(tm1, tm2, inx_tm, iny_tm, A_tm);

    (void)hipMemsetAsync(d_out, 0, sizeof(float), stream);

    ipot_sp3<<<dim3(BS), 512, 0, stream>>>(A_sp, out);
    ipot_tm_kernel<<<dim3(BS), 64, 0, stream>>>(A_tm, out);
}